// Round 1
// baseline (290.447 us; speedup 1.0000x reference)
//
#include <hip/hip_runtime.h>

#define NB 32
#define CC 64
#define TT 300
#define VV 25
#define HH 16
#define TPOUT 150
#define KH 4      // kernel//2
#define TC 4      // timesteps per k1 block

#define TPC 25    // selected rows per k2 chunk
#define NCHUNK 6
#define ROWS_MAX 57
#define SXW_LD 68 // padded leading dim (floats) to avoid bank conflicts

// ---------------- Kernel 1: xw[r][t][c] = sum_ci x[n][ci][t][v] * W[ci][c] ----
__global__ __launch_bounds__(256) void k1_xw(const float* __restrict__ x,
                                             const float* __restrict__ W,
                                             float* __restrict__ xw) {
    __shared__ float sW[64][64];        // [ci][cout]
    __shared__ float sx[64][TC * VV];   // [ci][tloc*25+v], row = 400B (16B aligned)
    const int n  = blockIdx.y;
    const int t0 = blockIdx.x * TC;

    for (int i = threadIdx.x; i < 64 * 64; i += 256) sW[i >> 6][i & 63] = W[i];

    const float* xbase = x + (size_t)n * (CC * TT * VV) + (size_t)t0 * VV;
    for (int j = threadIdx.x; j < 64 * TC * VV; j += 256) {
        int c = j / (TC * VV);
        int rem = j - c * (TC * VV);
        sx[c][rem] = xbase[(size_t)c * (TT * VV) + rem];
    }
    __syncthreads();

    const int cout = threadIdx.x & 63;
    const int g    = threadIdx.x >> 6;     // 0..3
    for (int tv4 = g; tv4 < (TC * VV) / 4; tv4 += 4) {
        float acc[4] = {0.f, 0.f, 0.f, 0.f};
#pragma unroll
        for (int c = 0; c < 64; ++c) {
            float w = sW[c][cout];
            float4 xs = *reinterpret_cast<const float4*>(&sx[c][tv4 * 4]);
            acc[0] += w * xs.x;
            acc[1] += w * xs.y;
            acc[2] += w * xs.z;
            acc[3] += w * xs.w;
        }
#pragma unroll
        for (int j = 0; j < 4; ++j) {
            int tv = tv4 * 4 + j;
            int tloc = tv / VV;
            int v = tv - tloc * VV;
            xw[((size_t)(n * VV + v) * TT + (t0 + tloc)) * CC + cout] = acc[j];
        }
    }
}

// ---------------- Kernel 2: banded attention per r ---------------------------
__global__ __launch_bounds__(256) void k2_attn(const float* __restrict__ xw,
                                               const float* __restrict__ alpha,
                                               const float* __restrict__ phi,
                                               float* __restrict__ out) {
    const int r = blockIdx.x;     // n*25 + v
    const int n = r / VV;
    const int v = r - n * VV;
    const float* xwr = xw + (size_t)r * (TT * CC);

    __shared__ float salpha[HH][SXW_LD];
    __shared__ float sphi[HH][SXW_LD];
    __shared__ float ssum[CC];
    __shared__ float sred[256];
    __shared__ float sxw[ROWS_MAX][SXW_LD];
    __shared__ float sx2[ROWS_MAX][HH];
    __shared__ float sx1[TPC][HH];
    __shared__ float sscore[TPC][9];
    __shared__ float scoef[TPC][10];

    const int tid = threadIdx.x;

    for (int i = tid; i < HH * CC; i += 256) {
        int h = i >> 6, c = i & 63;
        salpha[h][c] = alpha[i];
        sphi[h][c]   = phi[i];
    }
    // column sums over all 300 rows (background term)
    {
        int c = tid & 63, g = tid >> 6;
        float acc = 0.f;
        for (int t = g; t < TT; t += 4) acc += xwr[t * CC + c];
        sred[tid] = acc;
    }
    __syncthreads();
    if (tid < 64) ssum[tid] = sred[tid] + sred[tid + 64] + sred[tid + 128] + sred[tid + 192];

    for (int ch = 0; ch < NCHUNK; ++ch) {
        const int tp0 = ch * TPC;
        const int s_lo = max(0, 2 * tp0 - KH);
        const int s_hi = min(TT - 1, 2 * (tp0 + TPC - 1) + KH);
        const int rows = s_hi - s_lo + 1;

        __syncthreads();   // previous chunk consumers done
        // stage band window (float4, coalesced)
        for (int i = tid; i < rows * 16; i += 256) {
            int row = i >> 4, c4 = i & 15;
            *reinterpret_cast<float4*>(&sxw[row][c4 * 4]) =
                *reinterpret_cast<const float4*>(&xwr[(size_t)(s_lo + row) * CC + c4 * 4]);
        }
        __syncthreads();

        // x2 for all band rows, x1 for the 25 selected rows
        for (int i = tid; i < rows * HH; i += 256) {
            int row = i >> 4, h = i & 15;
            float acc = 0.f;
#pragma unroll
            for (int c = 0; c < CC; ++c) acc += sphi[h][c] * sxw[row][c];
            sx2[row][h] = acc;
        }
        for (int i = tid; i < TPC * HH; i += 256) {
            int tpl = i >> 4, h = i & 15;
            int row = 2 * (tp0 + tpl) - s_lo;
            float acc = 0.f;
#pragma unroll
            for (int c = 0; c < CC; ++c) acc += salpha[h][c] * sxw[row][c];
            sx1[tpl][h] = acc;
        }
        __syncthreads();

        // band scores: 225 (tpl, k) pairs in parallel
        if (tid < TPC * 9) {
            int tpl = tid / 9, k = tid - tpl * 9;
            int t = 2 * (tp0 + tpl);
            int s = t - KH + k;
            float sc = 0.f;
            if (s >= 0 && s < TT) {
                int row = s - s_lo;
#pragma unroll
                for (int h = 0; h < HH; ++h) sc += sx1[tpl][h] * sx2[row][h];
            }
            sscore[tpl][k] = sc;
        }
        __syncthreads();

        // softmax coefficients per selected row
        if (tid < TPC) {
            int tpl = tid;
            int t = 2 * (tp0 + tpl);
            float m = 0.f;   // background zeros participate in the max
            int nb = 0;
#pragma unroll
            for (int k = 0; k < 9; ++k) {
                int s = t - KH + k;
                if (s >= 0 && s < TT) { nb++; m = fmaxf(m, sscore[tpl][k]); }
            }
            float wbg = __expf(-m);
            float Z = (float)(TT - nb) * wbg;
            float e[9];
#pragma unroll
            for (int k = 0; k < 9; ++k) {
                int s = t - KH + k;
                float ek = (s >= 0 && s < TT) ? __expf(sscore[tpl][k] - m) : 0.f;
                e[k] = ek;
                Z += ek;
            }
            float inv = 1.f / Z;
#pragma unroll
            for (int k = 0; k < 9; ++k) {
                int s = t - KH + k;
                scoef[tpl][k] = (s >= 0 && s < TT) ? (e[k] - wbg) * inv : 0.f;
            }
            scoef[tpl][9] = wbg * inv;
        }
        __syncthreads();

        // out[tpl][c] = cbg*ssum[c] + sum_k coef_k * xw[s][c]
        for (int i = tid; i < TPC * CC; i += 256) {
            int tpl = i >> 6, c = i & 63;
            int t = 2 * (tp0 + tpl);
            int row0 = t - KH - s_lo;
            float val = scoef[tpl][9] * ssum[c];
#pragma unroll
            for (int k = 0; k < 9; ++k) {
                int row = row0 + k;
                row = min(max(row, 0), rows - 1);   // coef is 0 for invalid slots
                val += scoef[tpl][k] * sxw[row][c];
            }
            out[(size_t)n * (CC * TPOUT * VV) + (size_t)c * (TPOUT * VV) + (tp0 + tpl) * VV + v] = val;
        }
    }
}

extern "C" void kernel_launch(void* const* d_in, const int* in_sizes, int n_in,
                              void* d_out, int out_size, void* d_ws, size_t ws_size,
                              hipStream_t stream) {
    const float* x     = (const float*)d_in[0];
    const float* W     = (const float*)d_in[1];
    const float* alpha = (const float*)d_in[2];
    const float* phi   = (const float*)d_in[3];
    float* out = (float*)d_out;
    float* xw  = (float*)d_ws;   // needs 800*300*64*4 = 61.44 MB

    dim3 g1(TT / TC, NB);
    k1_xw<<<g1, 256, 0, stream>>>(x, W, xw);
    k2_attn<<<NB * VV, 256, 0, stream>>>(xw, alpha, phi, out);
}

// Round 2
// 179.222 us; speedup vs baseline: 1.6206x; 1.6206x over previous
//
#include <hip/hip_runtime.h>

#define NB 32
#define CC 64
#define TT 300
#define VV 25
#define HH 16
#define TPOUT 150
#define KH 4      // kernel//2
#define TC 4      // timesteps per k1 block

#define TPC 25    // selected rows per k2 chunk
#define NCHUNK 6
#define ROWS_MAX 57
#define SLD 68    // padded leading dim (floats): 68%32=4 -> conflict-light

// ---------------- Kernel 1: xw[r][t][c] = sum_ci x[n][ci][t][v] * W[ci][c] ----
__global__ __launch_bounds__(256) void k1_xw(const float* __restrict__ x,
                                             const float* __restrict__ W,
                                             float* __restrict__ xw) {
    __shared__ float sW[64][64];        // [ci][cout]
    __shared__ float sx[64][TC * VV];   // [ci][tloc*25+v]
    const int n  = blockIdx.y;
    const int t0 = blockIdx.x * TC;

    for (int i = threadIdx.x; i < 64 * 64; i += 256) sW[i >> 6][i & 63] = W[i];

    const float* xbase = x + (size_t)n * (CC * TT * VV) + (size_t)t0 * VV;
    for (int j = threadIdx.x; j < 64 * TC * VV; j += 256) {
        int c = j / (TC * VV);
        int rem = j - c * (TC * VV);
        sx[c][rem] = xbase[(size_t)c * (TT * VV) + rem];
    }
    __syncthreads();

    const int cout = threadIdx.x & 63;
    const int g    = threadIdx.x >> 6;     // 0..3
    for (int tv4 = g; tv4 < (TC * VV) / 4; tv4 += 4) {
        float acc[4] = {0.f, 0.f, 0.f, 0.f};
#pragma unroll
        for (int c = 0; c < 64; ++c) {
            float w = sW[c][cout];
            float4 xs = *reinterpret_cast<const float4*>(&sx[c][tv4 * 4]);
            acc[0] += w * xs.x;
            acc[1] += w * xs.y;
            acc[2] += w * xs.z;
            acc[3] += w * xs.w;
        }
#pragma unroll
        for (int j = 0; j < 4; ++j) {
            int tv = tv4 * 4 + j;
            int tloc = tv / VV;
            int v = tv - tloc * VV;
            xw[((size_t)(n * VV + v) * TT + (t0 + tloc)) * CC + cout] = acc[j];
        }
    }
}

// ---------------- Kernel 1b: ssum[r][c] = sum_t xw[r][t][c] ------------------
__global__ __launch_bounds__(256) void k1b_colsum(const float* __restrict__ xw,
                                                  float* __restrict__ ssum) {
    __shared__ float sred[256];
    const int r = blockIdx.x;
    const float* p = xw + (size_t)r * (TT * CC);
    const int c = threadIdx.x & 63, g = threadIdx.x >> 6;
    float acc = 0.f;
    for (int t = g; t < TT; t += 4) acc += p[(size_t)t * CC + c];
    sred[threadIdx.x] = acc;
    __syncthreads();
    if (threadIdx.x < 64)
        ssum[(size_t)r * CC + threadIdx.x] =
            sred[threadIdx.x] + sred[threadIdx.x + 64] +
            sred[threadIdx.x + 128] + sred[threadIdx.x + 192];
}

// ---------------- Kernel 2: banded attention, one (chunk, r) per block -------
__global__ __launch_bounds__(256) void k2_attn(const float* __restrict__ xw,
                                               const float* __restrict__ ssum,
                                               const float* __restrict__ alpha,
                                               const float* __restrict__ phi,
                                               float* __restrict__ tmp) {
    const int ch = blockIdx.x;    // 0..5
    const int r  = blockIdx.y;    // n*25 + v
    const float* xwr = xw + (size_t)r * (TT * CC);

    __shared__ __align__(16) float salpha[HH][SLD];
    __shared__ __align__(16) float sphi[HH][SLD];
    __shared__ __align__(16) float sxw[ROWS_MAX][SLD];
    __shared__ float sss[CC];
    __shared__ float sx2[ROWS_MAX][HH];
    __shared__ float sx1[TPC][HH];
    __shared__ float sscore[TPC][9];
    __shared__ float scoef[TPC][10];

    const int tid = threadIdx.x;
    const int tp0 = ch * TPC;
    const int s_lo = max(0, 2 * tp0 - KH);
    const int s_hi = min(TT - 1, 2 * (tp0 + TPC - 1) + KH);
    const int rows = s_hi - s_lo + 1;

    for (int i = tid; i < HH * CC; i += 256) {
        int h = i >> 6, c = i & 63;
        salpha[h][c] = alpha[i];
        sphi[h][c]   = phi[i];
    }
    if (tid < CC) sss[tid] = ssum[(size_t)r * CC + tid];
    // stage band window (float4, coalesced)
    for (int i = tid; i < rows * 16; i += 256) {
        int row = i >> 4, c4 = i & 15;
        *reinterpret_cast<float4*>(&sxw[row][c4 * 4]) =
            *reinterpret_cast<const float4*>(&xwr[(size_t)(s_lo + row) * CC + c4 * 4]);
    }
    __syncthreads();

    // x2 for all band rows, x1 for the 25 selected rows (float4 dots)
    for (int i = tid; i < rows * HH; i += 256) {
        int row = i >> 4, h = i & 15;
        const float4* ph = reinterpret_cast<const float4*>(&sphi[h][0]);
        const float4* pr = reinterpret_cast<const float4*>(&sxw[row][0]);
        float acc = 0.f;
#pragma unroll
        for (int k = 0; k < 16; ++k) {
            float4 a = ph[k], b = pr[k];
            acc += a.x * b.x + a.y * b.y + a.z * b.z + a.w * b.w;
        }
        sx2[row][h] = acc;
    }
    for (int i = tid; i < TPC * HH; i += 256) {
        int tpl = i >> 4, h = i & 15;
        int row = 2 * (tp0 + tpl) - s_lo;
        const float4* pa = reinterpret_cast<const float4*>(&salpha[h][0]);
        const float4* pr = reinterpret_cast<const float4*>(&sxw[row][0]);
        float acc = 0.f;
#pragma unroll
        for (int k = 0; k < 16; ++k) {
            float4 a = pa[k], b = pr[k];
            acc += a.x * b.x + a.y * b.y + a.z * b.z + a.w * b.w;
        }
        sx1[tpl][h] = acc;
    }
    __syncthreads();

    // band scores: 225 (tpl, k) pairs
    if (tid < TPC * 9) {
        int tpl = tid / 9, k = tid - tpl * 9;
        int t = 2 * (tp0 + tpl);
        int s = t - KH + k;
        float sc = 0.f;
        if (s >= 0 && s < TT) {
            int row = s - s_lo;
#pragma unroll
            for (int h = 0; h < HH; ++h) sc += sx1[tpl][h] * sx2[row][h];
        }
        sscore[tpl][k] = sc;
    }
    __syncthreads();

    // softmax coefficients per selected row (background zeros fold analytically)
    if (tid < TPC) {
        int tpl = tid;
        int t = 2 * (tp0 + tpl);
        float m = 0.f;
        int nb = 0;
#pragma unroll
        for (int k = 0; k < 9; ++k) {
            int s = t - KH + k;
            if (s >= 0 && s < TT) { nb++; m = fmaxf(m, sscore[tpl][k]); }
        }
        float wbg = __expf(-m);
        float Z = (float)(TT - nb) * wbg;
        float e[9];
#pragma unroll
        for (int k = 0; k < 9; ++k) {
            int s = t - KH + k;
            float ek = (s >= 0 && s < TT) ? __expf(sscore[tpl][k] - m) : 0.f;
            e[k] = ek;
            Z += ek;
        }
        float inv = 1.f / Z;
#pragma unroll
        for (int k = 0; k < 9; ++k) {
            int s = t - KH + k;
            scoef[tpl][k] = (s >= 0 && s < TT) ? (e[k] - wbg) * inv : 0.f;
        }
        scoef[tpl][9] = wbg * inv;
    }
    __syncthreads();

    // tmp[r][tp][c] = cbg*ssum[c] + sum_k coef_k * xw[s][c]   (fully coalesced)
    for (int i = tid; i < TPC * CC; i += 256) {
        int tpl = i >> 6, c = i & 63;
        int t = 2 * (tp0 + tpl);
        int row0 = t - KH - s_lo;
        float val = scoef[tpl][9] * sss[c];
#pragma unroll
        for (int k = 0; k < 9; ++k) {
            int row = row0 + k;
            row = min(max(row, 0), rows - 1);   // coef is 0 for invalid slots
            val += scoef[tpl][k] * sxw[row][c];
        }
        tmp[((size_t)r * TPOUT + (tp0 + tpl)) * CC + c] = val;
    }
}

// ---------------- Kernel 3: tmp[n][v][tp][c] -> out[n][c][tp][v] -------------
#define TPT 5
__global__ __launch_bounds__(256) void k3_transpose(const float* __restrict__ tmp,
                                                    float* __restrict__ out) {
    __shared__ float tile[VV][TPT][65];
    const int n = blockIdx.y;
    const int tp0 = blockIdx.x * TPT;
    const int tid = threadIdx.x;

    const float* src = tmp + (size_t)n * (VV * TPOUT * CC);
    for (int i = tid; i < VV * TPT * CC; i += 256) {
        int v = i / (TPT * CC);
        int rem = i - v * (TPT * CC);
        int tpl = rem >> 6, c = rem & 63;
        tile[v][tpl][c] = src[((size_t)v * TPOUT + tp0 + tpl) * CC + c];
    }
    __syncthreads();
    float* dst = out + (size_t)n * (CC * TPOUT * VV);
    for (int j = tid; j < CC * TPT * VV; j += 256) {
        int c = j / (TPT * VV);
        int rem = j - c * (TPT * VV);
        int tpl = rem / VV, v = rem - tpl * VV;
        dst[(size_t)c * (TPOUT * VV) + (tp0 + tpl) * VV + v] = tile[v][tpl][c];
    }
}

extern "C" void kernel_launch(void* const* d_in, const int* in_sizes, int n_in,
                              void* d_out, int out_size, void* d_ws, size_t ws_size,
                              hipStream_t stream) {
    const float* x     = (const float*)d_in[0];
    const float* W     = (const float*)d_in[1];
    const float* alpha = (const float*)d_in[2];
    const float* phi   = (const float*)d_in[3];
    float* out = (float*)d_out;

    float* xw   = (float*)d_ws;                       // 800*300*64 = 15,360,000 f
    float* ssum = xw + (size_t)800 * 300 * 64;        // 800*64     =     51,200 f
    float* tmp  = ssum + (size_t)800 * 64;            // 800*150*64 =  7,680,000 f
                                                      // total 92.36 MB

    dim3 g1(TT / TC, NB);
    k1_xw<<<g1, 256, 0, stream>>>(x, W, xw);
    k1b_colsum<<<NB * VV, 256, 0, stream>>>(xw, ssum);
    dim3 g2(NCHUNK, NB * VV);
    k2_attn<<<g2, 256, 0, stream>>>(xw, ssum, alpha, phi, tmp);
    dim3 g3(TPOUT / TPT, NB);
    k3_transpose<<<g3, 256, 0, stream>>>(tmp, out);
}

// Round 3
// 155.603 us; speedup vs baseline: 1.8666x; 1.1518x over previous
//
#include <hip/hip_runtime.h>

#define NB 32
#define CC 64
#define TT 300
#define VV 25
#define HH 16
#define H2 32      // alpha rows + phi rows
#define TPOUT 150
#define KH 4       // kernel//2
#define TC 4       // timesteps per k1 block

#define TPC 25     // selected rows per k2 chunk
#define NCHUNK 6
#define ROWS_MAX 57
#define ROWS_PAD 60
#define SLD 68     // sxw leading dim

// ---------------- Kernel 1: xw[r][t][c] = sum_ci x[n][ci][t][v] * W[ci][c] ----
// Outer-product register tiling: thread tile = 4 cout x 4 tv.
__global__ __launch_bounds__(256) void k1_xw(const float* __restrict__ x,
                                             const float* __restrict__ W,
                                             float* __restrict__ xw) {
    __shared__ float sW[64][64];        // [ci][cout]
    __shared__ float sx[64][TC * VV];   // [ci][tv], row = 400B (16B aligned)
    const int n  = blockIdx.y;
    const int t0 = blockIdx.x * TC;
    const int tid = threadIdx.x;

    // stage W (float4, coalesced)
    for (int i = tid; i < 1024; i += 256) {
        int row = i >> 4, c4 = i & 15;
        reinterpret_cast<float4*>(&sW[row][0])[c4] =
            reinterpret_cast<const float4*>(W)[i];
    }
    // stage x slice (float4, coalesced: 100 contiguous floats per ci)
    const float* xbase = x + (size_t)n * (CC * TT * VV) + (size_t)t0 * VV;
    for (int i = tid; i < 64 * 25; i += 256) {
        int ci = i / 25, f = i - ci * 25;
        reinterpret_cast<float4*>(&sx[ci][0])[f] =
            *reinterpret_cast<const float4*>(&xbase[(size_t)ci * (TT * VV) + f * 4]);
    }
    __syncthreads();

#pragma unroll
    for (int pass = 0; pass < 2; ++pass) {
        int tile = tid + pass * 256;
        if (tile < 400) {
            const int cg  = tile & 15;   // cout quad
            const int tv4 = tile >> 4;   // tv quad (0..24)
            float4 a0 = {0,0,0,0}, a1 = {0,0,0,0}, a2 = {0,0,0,0}, a3 = {0,0,0,0};
#pragma unroll
            for (int ci = 0; ci < 64; ++ci) {
                float4 w  = reinterpret_cast<const float4*>(&sW[ci][0])[cg];
                float4 xs = reinterpret_cast<const float4*>(&sx[ci][0])[tv4];
                a0.x = fmaf(w.x, xs.x, a0.x); a0.y = fmaf(w.x, xs.y, a0.y);
                a0.z = fmaf(w.x, xs.z, a0.z); a0.w = fmaf(w.x, xs.w, a0.w);
                a1.x = fmaf(w.y, xs.x, a1.x); a1.y = fmaf(w.y, xs.y, a1.y);
                a1.z = fmaf(w.y, xs.z, a1.z); a1.w = fmaf(w.y, xs.w, a1.w);
                a2.x = fmaf(w.z, xs.x, a2.x); a2.y = fmaf(w.z, xs.y, a2.y);
                a2.z = fmaf(w.z, xs.z, a2.z); a2.w = fmaf(w.z, xs.w, a2.w);
                a3.x = fmaf(w.w, xs.x, a3.x); a3.y = fmaf(w.w, xs.y, a3.y);
                a3.z = fmaf(w.w, xs.z, a3.z); a3.w = fmaf(w.w, xs.w, a3.w);
            }
            // stores: float4 along cout (contiguous) per tv
#pragma unroll
            for (int b = 0; b < 4; ++b) {
                int tv = 4 * tv4 + b;
                int tloc = tv / 25, v = tv - tloc * 25;
                float4 st;
                st.x = (b == 0) ? a0.x : (b == 1) ? a0.y : (b == 2) ? a0.z : a0.w;
                st.y = (b == 0) ? a1.x : (b == 1) ? a1.y : (b == 2) ? a1.z : a1.w;
                st.z = (b == 0) ? a2.x : (b == 1) ? a2.y : (b == 2) ? a2.z : a2.w;
                st.w = (b == 0) ? a3.x : (b == 1) ? a3.y : (b == 2) ? a3.z : a3.w;
                size_t base = ((size_t)(n * VV + v) * TT + (t0 + tloc)) * CC + 4 * cg;
                *reinterpret_cast<float4*>(&xw[base]) = st;
            }
        }
    }
}

// ---------------- Kernel 1b: ssum[r][c] = sum_t xw[r][t][c] ------------------
__global__ __launch_bounds__(256) void k1b_colsum(const float* __restrict__ xw,
                                                  float* __restrict__ ssum) {
    __shared__ float sred[256];
    const int r = blockIdx.x;
    const float* p = xw + (size_t)r * (TT * CC);
    const int c = threadIdx.x & 63, g = threadIdx.x >> 6;
    float acc = 0.f;
    for (int t = g; t < TT; t += 4) acc += p[(size_t)t * CC + c];
    sred[threadIdx.x] = acc;
    __syncthreads();
    if (threadIdx.x < 64)
        ssum[(size_t)r * CC + threadIdx.x] =
            sred[threadIdx.x] + sred[threadIdx.x + 64] +
            sred[threadIdx.x + 128] + sred[threadIdx.x + 192];
}

// ---------------- Kernel 2: banded attention, one (chunk, r) per block -------
__global__ __launch_bounds__(256) void k2_attn(const float* __restrict__ xw,
                                               const float* __restrict__ ssum,
                                               const float* __restrict__ alpha,
                                               const float* __restrict__ phi,
                                               float* __restrict__ tmp) {
    const int ch = blockIdx.x;    // 0..5
    const int r  = blockIdx.y;    // n*25 + v
    const float* xwr = xw + (size_t)r * (TT * CC);

    __shared__ __align__(16) float sxw[ROWS_MAX][SLD];       // band, row-major
    __shared__ __align__(16) float sxwT[CC][ROWS_PAD];       // band, transposed
    __shared__ __align__(16) float sAPT[CC][36];             // [c][h], h<16 alpha, h>=16 phi
    __shared__ __align__(16) float sxap[ROWS_PAD][36];       // [row][h]
    __shared__ float sss[CC];
    __shared__ float sscore[TPC][9];
    __shared__ float scoef[TPC][10];

    const int tid = threadIdx.x;
    const int tp0 = ch * TPC;
    const int s_lo = max(0, 2 * tp0 - KH);
    const int s_hi = min(TT - 1, 2 * (tp0 + TPC - 1) + KH);
    const int rows = s_hi - s_lo + 1;

    // ---- stage ----
    for (int i = tid; i < rows * 16; i += 256) {
        int row = i >> 4, c4 = i & 15;
        *reinterpret_cast<float4*>(&sxw[row][c4 * 4]) =
            *reinterpret_cast<const float4*>(&xwr[(size_t)(s_lo + row) * CC + c4 * 4]);
    }
    for (int i = tid; i < CC * ROWS_PAD; i += 256) {
        int c = i & 63, row = i >> 6;
        int sg = min(s_lo + row, TT - 1);
        sxwT[c][row] = xwr[(size_t)sg * CC + c];
    }
    for (int i = tid; i < H2 * CC; i += 256) {
        int c = i >> 5, h = i & 31;
        float v = (h < HH) ? alpha[h * CC + c] : phi[(h - HH) * CC + c];
        sAPT[c][h] = v;
    }
    if (tid < CC) sss[tid] = ssum[(size_t)r * CC + tid];
    __syncthreads();

    // ---- in-block xap GEMM: sxap[row][h] = sum_c AP[h][c] * xw_band[row][c] ----
    if (tid < 15 * 8) {
        const int tl4 = tid % 15;    // row quad
        const int hq  = tid / 15;    // h quad
        float4 b0 = {0,0,0,0}, b1 = {0,0,0,0}, b2 = {0,0,0,0}, b3 = {0,0,0,0};
#pragma unroll
        for (int c = 0; c < CC; ++c) {
            float4 ap = reinterpret_cast<const float4*>(&sAPT[c][0])[hq];
            float4 xs = reinterpret_cast<const float4*>(&sxwT[c][0])[tl4];
            b0.x = fmaf(xs.x, ap.x, b0.x); b0.y = fmaf(xs.x, ap.y, b0.y);
            b0.z = fmaf(xs.x, ap.z, b0.z); b0.w = fmaf(xs.x, ap.w, b0.w);
            b1.x = fmaf(xs.y, ap.x, b1.x); b1.y = fmaf(xs.y, ap.y, b1.y);
            b1.z = fmaf(xs.y, ap.z, b1.z); b1.w = fmaf(xs.y, ap.w, b1.w);
            b2.x = fmaf(xs.z, ap.x, b2.x); b2.y = fmaf(xs.z, ap.y, b2.y);
            b2.z = fmaf(xs.z, ap.z, b2.z); b2.w = fmaf(xs.z, ap.w, b2.w);
            b3.x = fmaf(xs.w, ap.x, b3.x); b3.y = fmaf(xs.w, ap.y, b3.y);
            b3.z = fmaf(xs.w, ap.z, b3.z); b3.w = fmaf(xs.w, ap.w, b3.w);
        }
        reinterpret_cast<float4*>(&sxap[4 * tl4 + 0][0])[hq] = b0;
        reinterpret_cast<float4*>(&sxap[4 * tl4 + 1][0])[hq] = b1;
        reinterpret_cast<float4*>(&sxap[4 * tl4 + 2][0])[hq] = b2;
        reinterpret_cast<float4*>(&sxap[4 * tl4 + 3][0])[hq] = b3;
    }
    __syncthreads();

    // ---- band scores: 225 (tpl, k) pairs ----
    if (tid < TPC * 9) {
        int tpl = tid / 9, k = tid - tpl * 9;
        int t = 2 * (tp0 + tpl);
        int s = t - KH + k;
        float sc = 0.f;
        if (s >= 0 && s < TT) {
            int rt = t - s_lo;
            int rs = s - s_lo;
#pragma unroll
            for (int q = 0; q < 4; ++q) {
                float4 x1 = reinterpret_cast<const float4*>(&sxap[rt][0])[q];
                float4 x2 = reinterpret_cast<const float4*>(&sxap[rs][0])[q + 4];
                sc += x1.x * x2.x + x1.y * x2.y + x1.z * x2.z + x1.w * x2.w;
            }
        }
        sscore[tpl][k] = sc;
    }
    __syncthreads();

    // ---- softmax coefficients (background zeros fold analytically) ----
    if (tid < TPC) {
        int tpl = tid;
        int t = 2 * (tp0 + tpl);
        float m = 0.f;
        int nb = 0;
#pragma unroll
        for (int k = 0; k < 9; ++k) {
            int s = t - KH + k;
            if (s >= 0 && s < TT) { nb++; m = fmaxf(m, sscore[tpl][k]); }
        }
        float wbg = __expf(-m);
        float Z = (float)(TT - nb) * wbg;
        float e[9];
#pragma unroll
        for (int k = 0; k < 9; ++k) {
            int s = t - KH + k;
            float ek = (s >= 0 && s < TT) ? __expf(sscore[tpl][k] - m) : 0.f;
            e[k] = ek;
            Z += ek;
        }
        float inv = 1.f / Z;
#pragma unroll
        for (int k = 0; k < 9; ++k) {
            int s = t - KH + k;
            scoef[tpl][k] = (s >= 0 && s < TT) ? (e[k] - wbg) * inv : 0.f;
        }
        scoef[tpl][9] = wbg * inv;
    }
    __syncthreads();

    // ---- output: tmp[r][tp][c] ----
    for (int i = tid; i < TPC * CC; i += 256) {
        int tpl = i >> 6, c = i & 63;
        int t = 2 * (tp0 + tpl);
        int row0 = t - KH - s_lo;
        float val = scoef[tpl][9] * sss[c];
#pragma unroll
        for (int k = 0; k < 9; ++k) {
            int row = row0 + k;
            row = min(max(row, 0), rows - 1);   // coef is 0 for invalid slots
            val += scoef[tpl][k] * sxw[row][c];
        }
        tmp[((size_t)r * TPOUT + (tp0 + tpl)) * CC + c] = val;
    }
}

// ---------------- Kernel 3: tmp[n][v][tp][c] -> out[n][c][tp][v] -------------
#define TPT 5
__global__ __launch_bounds__(256) void k3_transpose(const float* __restrict__ tmp,
                                                    float* __restrict__ out) {
    __shared__ float tile[VV][TPT][65];
    const int n = blockIdx.y;
    const int tp0 = blockIdx.x * TPT;
    const int tid = threadIdx.x;

    const float* src = tmp + (size_t)n * (VV * TPOUT * CC);
    for (int i = tid; i < VV * TPT * CC; i += 256) {
        int v = i / (TPT * CC);
        int rem = i - v * (TPT * CC);
        int tpl = rem >> 6, c = rem & 63;
        tile[v][tpl][c] = src[((size_t)v * TPOUT + tp0 + tpl) * CC + c];
    }
    __syncthreads();
    float* dst = out + (size_t)n * (CC * TPOUT * VV);
    for (int j = tid; j < CC * TPT * VV; j += 256) {
        int c = j / (TPT * VV);
        int rem = j - c * (TPT * VV);
        int tpl = rem / VV, v = rem - tpl * VV;
        dst[(size_t)c * (TPOUT * VV) + (tp0 + tpl) * VV + v] = tile[v][tpl][c];
    }
}

extern "C" void kernel_launch(void* const* d_in, const int* in_sizes, int n_in,
                              void* d_out, int out_size, void* d_ws, size_t ws_size,
                              hipStream_t stream) {
    const float* x     = (const float*)d_in[0];
    const float* W     = (const float*)d_in[1];
    const float* alpha = (const float*)d_in[2];
    const float* phi   = (const float*)d_in[3];
    float* out = (float*)d_out;

    float* xw   = (float*)d_ws;                       // 800*300*64 = 15,360,000 f
    float* ssum = xw + (size_t)800 * 300 * 64;        // 800*64     =     51,200 f
    float* tmp  = ssum + (size_t)800 * 64;            // 800*150*64 =  7,680,000 f
                                                      // total 92.36 MB (as round 2)

    dim3 g1(TT / TC, NB);
    k1_xw<<<g1, 256, 0, stream>>>(x, W, xw);
    k1b_colsum<<<NB * VV, 256, 0, stream>>>(xw, ssum);
    dim3 g2(NCHUNK, NB * VV);
    k2_attn<<<g2, 256, 0, stream>>>(xw, ssum, alpha, phi, tmp);
    dim3 g3(TPOUT / TPT, NB);
    k3_transpose<<<g3, 256, 0, stream>>>(tmp, out);
}